// Round 9
// baseline (100.515 us; speedup 1.0000x reference)
//
#include <hip/hip_runtime.h>
#include <hip/hip_bf16.h>

#define NN 12288
#define ED 256
#define ES 32
#define NPC (NN - 1)      // parent->child edges: edges rows NN..2NN-2 are (parent[i], i), i=1..NN-1
#define BLK 256

typedef __hip_bfloat16 bf16;
typedef __attribute__((ext_vector_type(8))) short s8v;            // 8 x bf16 (4 VGPR)
typedef __attribute__((ext_vector_type(8))) unsigned short u8v;
typedef __attribute__((ext_vector_type(4))) float f4v;

// ---- dtype detect (HW-verified rounds 0-2,5-8): f32 tensors reinterpreted
// as bf16 contain mantissa words with random exponents -> huge magnitudes.
// Wave-uniform; in_sizes is in ELEMENTS so dtype cannot be resolved on host.
__device__ __forceinline__ bool detect_f32(const void* W1) {
    const unsigned short* p = (const unsigned short*)W1 + (threadIdx.x & 63) * 8;
    u8v v = *(const u8v*)p;
    int huge = 0;
#pragma unroll
    for (int i = 0; i < 8; ++i) {
        unsigned short m = (unsigned short)(v[i] & 0x7fff);
        huge |= (m >= 0x4620);   // |bf16| >= 10240.0
    }
    return __any(huge) != 0;
}

__device__ __forceinline__ float ldv(const void* p, int i, bool f32) {
    return f32 ? ((const float*)p)[i] : __bfloat162float(((const bf16*)p)[i]);
}

__device__ __forceinline__ unsigned short f2bf(float f) {   // RNE f32->bf16 bits
    bf16 h = __float2bfloat16(f);
    return __builtin_bit_cast(unsigned short, h);
}

// ---- k0: ALL prep in one dispatch, no pre-zero needed anywhere.
// Blocks 0..47: OWNERSHIP histogram — block b owns deg[256b..256b+256).
// Zero 256 LDS counters, scan all NPC parents (coalesced, L2-hot), LDS-atomic
// in-range hits, plain-store the chunk. No global atomics -> no memset(deg).
// Blocks 48..191: zero acc1+acc2 (disjoint buffers, safe to share dispatch).
__global__ __launch_bounds__(BLK)
void k0(const int* __restrict__ edges, unsigned* __restrict__ deg,
        float4* __restrict__ accz) {
    unsigned b = blockIdx.x;
    if (b < 48) {
        __shared__ unsigned cnt[BLK];
        int tt = threadIdx.x;
        cnt[tt] = 0u;
        __syncthreads();
        int lo = b * BLK, hi = lo + BLK;
        for (int e = tt; e < NPC; e += BLK) {
            int p = edges[2 * (NN + e)];              // parent of child e+1
            if (p >= lo && p < hi) atomicAdd(&cnt[p - lo], 1u);
        }
        __syncthreads();
        deg[lo + tt] = cnt[tt];
    } else {
        const unsigned n4 = 2u * NN * ES / 4;         // acc1+acc2 as float4
        unsigned i = (b - 48) * BLK + threadIdx.x;
        const unsigned stride = (gridDim.x - 48) * BLK;
        for (; i < n4; i += stride) accz[i] = make_float4(0.f, 0.f, 0.f, 0.f);
    }
}

// ---- k1: X1 = emb@W1 + b1 via bf16 MFMA (f32 accum) + FUSED scatter1:
// acc1[parent(n)] += w * X1[n] issued straight from the MFMA accumulator
// registers. Block = 64 nodes (4 waves x 16). W1^T staged in LDS bf16
// [32 j][256 k], 16B-block XOR swizzle (blk ^= j&7): reads 2 lanes/bank (free).
__global__ __launch_bounds__(BLK)
void k1(const int* __restrict__ node_ids, const int* __restrict__ edges,
        const void* __restrict__ table, const void* __restrict__ W1,
        const void* __restrict__ b1, const unsigned* __restrict__ deg,
        float* __restrict__ X, float* __restrict__ acc1) {
    __shared__ unsigned short sW1T[ES * ED];          // 16 KB
    bool f32 = detect_f32(W1);
    int tt = threadIdx.x;

    // stage W1^T (bf16, swizzled): thread (j = tt&31, kc = tt>>5) does 4 blocks
    {
        int j = tt & 31, kc = tt >> 5;
        for (int it = 0; it < 4; ++it) {
            int kb = kc + 8 * it;                     // 16B block = 8 k values
            u8v v;
            if (f32) {
                const float* w = (const float*)W1;
#pragma unroll
                for (int e = 0; e < 8; ++e) v[e] = f2bf(w[(kb * 8 + e) * ES + j]);
            } else {
                const unsigned short* w = (const unsigned short*)W1;
#pragma unroll
                for (int e = 0; e < 8; ++e) v[e] = w[(kb * 8 + e) * ES + j];
            }
            *(u8v*)&sW1T[j * ED + ((kb ^ (j & 7)) * 8)] = v;
        }
    }
    __syncthreads();

    // MFMA: wave computes 16 nodes x 32 cols. A row q = node n0+q, k-offset hi*8.
    int lane = tt & 63;
    int q = lane & 15, hi = lane >> 4;
    int n0 = blockIdx.x * 64 + (tt >> 6) * 16;
    size_t id = (size_t)node_ids[n0 + q];
    f4v a0 = {0.f, 0.f, 0.f, 0.f}, a1 = {0.f, 0.f, 0.f, 0.f};
    int sw = q & 7;
    if (f32) {
        const float* e = (const float*)table + id * ED + hi * 8;
#pragma unroll
        for (int s = 0; s < 8; ++s) {
            f4v e0 = *(const f4v*)(e + s * 32);
            f4v e1 = *(const f4v*)(e + s * 32 + 4);
            u8v av;
#pragma unroll
            for (int i = 0; i < 4; ++i) { av[i] = f2bf(e0[i]); av[4 + i] = f2bf(e1[i]); }
            int blk = (hi + 4 * s) ^ sw;
            s8v b0  = *(const s8v*)&sW1T[q * ED + blk * 8];
            s8v b1v = *(const s8v*)&sW1T[(q + 16) * ED + blk * 8];
            s8v a = __builtin_bit_cast(s8v, av);
            a0 = __builtin_amdgcn_mfma_f32_16x16x32_bf16(a, b0,  a0, 0, 0, 0);
            a1 = __builtin_amdgcn_mfma_f32_16x16x32_bf16(a, b1v, a1, 0, 0, 0);
        }
    } else {
        const short* e = (const short*)table + id * ED + hi * 8;
#pragma unroll
        for (int s = 0; s < 8; ++s) {
            s8v a = *(const s8v*)(e + s * 32);
            int blk = (hi + 4 * s) ^ sw;
            s8v b0  = *(const s8v*)&sW1T[q * ED + blk * 8];
            s8v b1v = *(const s8v*)&sW1T[(q + 16) * ED + blk * 8];
            a0 = __builtin_amdgcn_mfma_f32_16x16x32_bf16(a, b0,  a0, 0, 0, 0);
            a1 = __builtin_amdgcn_mfma_f32_16x16x32_bf16(a, b1v, a1, 0, 0, 0);
        }
    }
    // C/D mapping: col = lane&15, row = (lane>>4)*4 + i  [m89/m91-verified]
    float bv0 = ldv(b1, q, f32), bv1 = ldv(b1, q + 16, f32);
#pragma unroll
    for (int i = 0; i < 4; ++i) {
        int n = n0 + hi * 4 + i;
        float x0 = a0[i] + bv0, x1 = a1[i] + bv1;
        X[n * ES + q]      = x0;
        X[n * ES + q + 16] = x1;
        if (n > 0) {                                  // node n is child of edge n-1
            int r = edges[2 * (NN + n - 1)];          // parent (16 lanes share -> L1 broadcast)
            float w = rsqrtf((float)deg[r] + 1.f) * rsqrtf((float)deg[n] + 1.f);
            atomicAdd(&acc1[r * ES + q],      w * x0);
            atomicAdd(&acc1[r * ES + q + 16], w * x1);
        }
    }
}

// ---- k3: per pc edge (c = e+1), h1[c] = relu(acc1[c] + (1/deg_c) X1[c]);
// X2[c] via shfl mat-vec against LDS W2; scatter w_rc * X2[c] into acc2[r].
__global__ __launch_bounds__(BLK)
void k3(const int* __restrict__ edges, const void* __restrict__ W1,
        const void* __restrict__ W2, const void* __restrict__ b2,
        const unsigned* __restrict__ deg, const float* __restrict__ acc1,
        const float* __restrict__ X, float* __restrict__ acc2) {
    __shared__ float sW2[ES * 33];                    // [k][j], padded: conflict-free j-reads
    __shared__ float sB[ES];
    bool f32 = detect_f32(W1);
    int tt = threadIdx.x;
    for (int i = tt; i < ES * ES; i += BLK) sW2[(i >> 5) * 33 + (i & 31)] = ldv(W2, i, f32);
    if (tt < ES) sB[tt] = ldv(b2, tt, f32);
    __syncthreads();
    unsigned t = blockIdx.x * BLK + tt;
    if (t >= (unsigned)NPC * ES) return;
    int e = t >> 5, j = t & 31;
    int c = e + 1;
    int r = edges[2 * (NN + e)];
    float rc = rsqrtf((float)deg[c] + 1.f);
    float h = fmaxf(acc1[c * ES + j] + (rc * rc) * X[c * ES + j], 0.f);
    float x2 = sB[j];
    #pragma unroll
    for (int k = 0; k < ES; ++k)
        x2 += __shfl(h, k, ES) * sW2[k * 33 + j];
    float w = rsqrtf((float)deg[r] + 1.f) * rc;
    atomicAdd(&acc2[r * ES + j], w * x2);
}

// ---- k4: out[n] = relu(acc2[n] + (1/deg_n) * X2[n]); X2[n] recomputed.
// Output dtype follows input dtype (f32 path passed rounds 0-2,5-8).
__global__ __launch_bounds__(BLK)
void k4(const void* __restrict__ W1, const void* __restrict__ W2,
        const void* __restrict__ b2, const unsigned* __restrict__ deg,
        const float* __restrict__ acc1, const float* __restrict__ X,
        const float* __restrict__ acc2, void* __restrict__ out) {
    __shared__ float sW2[ES * 33];
    __shared__ float sB[ES];
    bool f32 = detect_f32(W1);
    int tt = threadIdx.x;
    for (int i = tt; i < ES * ES; i += BLK) sW2[(i >> 5) * 33 + (i & 31)] = ldv(W2, i, f32);
    if (tt < ES) sB[tt] = ldv(b2, tt, f32);
    __syncthreads();
    unsigned t = blockIdx.x * BLK + tt;               // exact grid: NN*ES threads
    int n = t >> 5, j = t & 31;
    float rn = rsqrtf((float)deg[n] + 1.f);
    float sw = rn * rn;
    float h = fmaxf(acc1[n * ES + j] + sw * X[n * ES + j], 0.f);
    float x2 = sB[j];
    #pragma unroll
    for (int k = 0; k < ES; ++k)
        x2 += __shfl(h, k, ES) * sW2[k * 33 + j];
    float v = fmaxf(acc2[n * ES + j] + sw * x2, 0.f);
    if (f32) ((float*)out)[t] = v;
    else     ((bf16*)out)[t]  = __float2bfloat16(v);
}

extern "C" void kernel_launch(void* const* d_in, const int* in_sizes, int n_in,
                              void* d_out, int out_size, void* d_ws, size_t ws_size,
                              hipStream_t stream) {
    const int* node_ids = (const int*)d_in[0];
    const int* edges    = (const int*)d_in[1];
    const void* table   = d_in[2];
    const void* W1      = d_in[3];
    const void* b1      = d_in[4];
    const void* W2      = d_in[5];
    const void* b2      = d_in[6];

    // ws layout: [deg u32 NN][acc1 f32 NN*ES][acc2 f32 NN*ES][X f32 NN*ES]
    char* ws = (char*)d_ws;
    unsigned* deg = (unsigned*)ws;
    float* acc1   = (float*)(ws + (size_t)NN * 4);
    float* acc2   = acc1 + (size_t)NN * ES;
    float* X      = acc2 + (size_t)NN * ES;

    const int g_mfma = NN / 64;                       // 192 blocks, 64 nodes each
    const int g_node = NN * ES / BLK;                 // 1536, exact
    const int g_edge = (NPC * ES + BLK - 1) / BLK;    // 1536, last block partial

    k0<<<192,    BLK, 0, stream>>>(edges, deg, (float4*)acc1);
    k1<<<g_mfma, BLK, 0, stream>>>(node_ids, edges, table, W1, b1, deg, X, acc1);
    k3<<<g_edge, BLK, 0, stream>>>(edges, W1, W2, b2, deg, acc1, X, acc2);
    k4<<<g_node, BLK, 0, stream>>>(W1, W2, b2, deg, acc1, X, acc2, d_out);
}

// Round 10
// 89.473 us; speedup vs baseline: 1.1234x; 1.1234x over previous
//
#include <hip/hip_runtime.h>
#include <hip/hip_bf16.h>

#define NN 12288
#define ED 256
#define ES 32
#define NPC (NN - 1)      // parent->child edges: edges rows NN..2NN-2 are (parent[i], i), i=1..NN-1
#define BLK 256

typedef __hip_bfloat16 bf16;
typedef __attribute__((ext_vector_type(8))) short s8v;            // 8 x bf16 (4 VGPR)
typedef __attribute__((ext_vector_type(8))) unsigned short u8v;
typedef __attribute__((ext_vector_type(4))) float f4v;

// ---- dtype detect (HW-verified rounds 0-2,5-9): f32 tensors reinterpreted
// as bf16 contain mantissa words with random exponents -> huge magnitudes.
// Wave-uniform; in_sizes is in ELEMENTS so dtype cannot be resolved on host.
__device__ __forceinline__ bool detect_f32(const void* W1) {
    const unsigned short* p = (const unsigned short*)W1 + (threadIdx.x & 63) * 8;
    u8v v = *(const u8v*)p;
    int huge = 0;
#pragma unroll
    for (int i = 0; i < 8; ++i) {
        unsigned short m = (unsigned short)(v[i] & 0x7fff);
        huge |= (m >= 0x4620);   // |bf16| >= 10240.0
    }
    return __any(huge) != 0;
}

__device__ __forceinline__ float ldv(const void* p, int i, bool f32) {
    return f32 ? ((const float*)p)[i] : __bfloat162float(((const bf16*)p)[i]);
}

__device__ __forceinline__ unsigned short f2bf(float f) {   // RNE f32->bf16 bits
    bf16 h = __float2bfloat16(f);
    return __builtin_bit_cast(unsigned short, h);
}

// ---- k1: ALL prep folded in + X1 = emb@W1 + b1 via bf16 MFMA (f32 accum).
//  (a) zero acc1+acc2: 4 float4 plain stores/thread (consumed next dispatch);
//  (b) deg OWNERSHIP histogram: block b owns deg[64b..64b+64). LDS counters
//      (no pre-zeroed global needed). Latency fix vs r7/r9: batch 8
//      INDEPENDENT parent loads into registers, then test — 6 batches of
//      overlapped loads instead of 48 serial L2 round-trips;
//  (c) MFMA X1: W1^T in LDS bf16 [32 j][256 k], 16B-block XOR swizzle
//      (blk ^= j&7, reads 2 lanes/bank = free). Block = 64 nodes, 4 waves.
__global__ __launch_bounds__(BLK)
void k1(const int* __restrict__ node_ids, const int* __restrict__ edges,
        const void* __restrict__ table, const void* __restrict__ W1,
        const void* __restrict__ b1, unsigned* __restrict__ deg,
        float* __restrict__ X, float4* __restrict__ accz) {
    __shared__ unsigned short sW1T[ES * ED];          // 16 KB
    __shared__ unsigned cnt[64];
    bool f32 = detect_f32(W1);
    int tt = threadIdx.x;
    if (tt < 64) cnt[tt] = 0u;

    // (a) zero acc1+acc2: 196608 float4 over 49152 threads = 4 each
    {
        unsigned tid = blockIdx.x * BLK + tt;
        const unsigned n4 = 2u * NN * ES / 4;
        for (unsigned i = tid; i < n4; i += 192u * BLK)
            accz[i] = make_float4(0.f, 0.f, 0.f, 0.f);
    }

    // (c-stage) W1^T (bf16, swizzled): thread (j = tt&31, kc = tt>>5), 4 blocks
    {
        int j = tt & 31, kc = tt >> 5;
        for (int it = 0; it < 4; ++it) {
            int kb = kc + 8 * it;                     // 16B block = 8 k values
            u8v v;
            if (f32) {
                const float* w = (const float*)W1;
#pragma unroll
                for (int e = 0; e < 8; ++e) v[e] = f2bf(w[(kb * 8 + e) * ES + j]);
            } else {
                const unsigned short* w = (const unsigned short*)W1;
#pragma unroll
                for (int e = 0; e < 8; ++e) v[e] = w[(kb * 8 + e) * ES + j];
            }
            *(u8v*)&sW1T[j * ED + ((kb ^ (j & 7)) * 8)] = v;
        }
    }
    __syncthreads();                                  // covers cnt zero + sW1T

    // (b) ownership histogram, batched independent loads
    {
        int lo = blockIdx.x * 64;
        for (int base = 0; base < 48; base += 8) {
            int pb[8];
#pragma unroll
            for (int u = 0; u < 8; ++u) {
                int e = tt + (base + u) * BLK;
                pb[u] = (e < NPC) ? edges[2 * (NN + e)] : -1;
            }
#pragma unroll
            for (int u = 0; u < 8; ++u) {
                int p = pb[u] - lo;
                if (p >= 0 && p < 64) atomicAdd(&cnt[p], 1u);
            }
        }
    }

    // (c) MFMA: wave computes 16 nodes x 32 cols. A row q, k-offset hi*8.
    int lane = tt & 63;
    int q = lane & 15, hi = lane >> 4;
    int n0 = blockIdx.x * 64 + (tt >> 6) * 16;
    size_t id = (size_t)node_ids[n0 + q];
    f4v a0 = {0.f, 0.f, 0.f, 0.f}, a1 = {0.f, 0.f, 0.f, 0.f};
    int sw = q & 7;
    if (f32) {
        const float* e = (const float*)table + id * ED + hi * 8;
#pragma unroll
        for (int s = 0; s < 8; ++s) {
            f4v e0 = *(const f4v*)(e + s * 32);
            f4v e1 = *(const f4v*)(e + s * 32 + 4);
            u8v av;
#pragma unroll
            for (int i = 0; i < 4; ++i) { av[i] = f2bf(e0[i]); av[4 + i] = f2bf(e1[i]); }
            int blk = (hi + 4 * s) ^ sw;
            s8v b0  = *(const s8v*)&sW1T[q * ED + blk * 8];
            s8v b1v = *(const s8v*)&sW1T[(q + 16) * ED + blk * 8];
            s8v a = __builtin_bit_cast(s8v, av);
            a0 = __builtin_amdgcn_mfma_f32_16x16x32_bf16(a, b0,  a0, 0, 0, 0);
            a1 = __builtin_amdgcn_mfma_f32_16x16x32_bf16(a, b1v, a1, 0, 0, 0);
        }
    } else {
        const short* e = (const short*)table + id * ED + hi * 8;
#pragma unroll
        for (int s = 0; s < 8; ++s) {
            s8v a = *(const s8v*)(e + s * 32);
            int blk = (hi + 4 * s) ^ sw;
            s8v b0  = *(const s8v*)&sW1T[q * ED + blk * 8];
            s8v b1v = *(const s8v*)&sW1T[(q + 16) * ED + blk * 8];
            a0 = __builtin_amdgcn_mfma_f32_16x16x32_bf16(a, b0,  a0, 0, 0, 0);
            a1 = __builtin_amdgcn_mfma_f32_16x16x32_bf16(a, b1v, a1, 0, 0, 0);
        }
    }
    // C/D mapping: col = lane&15, row = (lane>>4)*4 + i  [m89/m91-verified]
    float bv0 = ldv(b1, q, f32), bv1 = ldv(b1, q + 16, f32);
#pragma unroll
    for (int i = 0; i < 4; ++i) {
        int n = n0 + hi * 4 + i;
        X[n * ES + q]      = a0[i] + bv0;
        X[n * ES + q + 16] = a1[i] + bv1;
    }

    __syncthreads();                                  // all cnt atomics done
    if (tt < 64) deg[blockIdx.x * 64 + tt] = cnt[tt]; // plain store, k2 reads next
}

// ---- k2 (round-6 body, best coalescing measured): acc1[r] += w_rc * X1[c]
// per pc edge. c = e+1 by construction -> X/deg[c] coalesced; wave = 2 edges
// -> atomics land in 2x128B segments.
__global__ __launch_bounds__(BLK)
void k2(const int* __restrict__ edges, const unsigned* __restrict__ deg,
        const float* __restrict__ X, float* __restrict__ acc1) {
    unsigned t = blockIdx.x * BLK + threadIdx.x;
    if (t >= (unsigned)NPC * ES) return;
    int e = t >> 5, k = t & 31;
    int c = e + 1;
    int r = edges[2 * (NN + e)];                      // parent (wave-broadcast load)
    float w = rsqrtf((float)deg[r] + 1.f) * rsqrtf((float)deg[c] + 1.f);
    atomicAdd(&acc1[r * ES + k], w * X[c * ES + k]);
}

// ---- k3: per pc edge (c = e+1), h1[c] = relu(acc1[c] + (1/deg_c) X1[c]);
// X2[c] via shfl mat-vec against LDS W2; scatter w_rc * X2[c] into acc2[r].
__global__ __launch_bounds__(BLK)
void k3(const int* __restrict__ edges, const void* __restrict__ W1,
        const void* __restrict__ W2, const void* __restrict__ b2,
        const unsigned* __restrict__ deg, const float* __restrict__ acc1,
        const float* __restrict__ X, float* __restrict__ acc2) {
    __shared__ float sW2[ES * 33];                    // [k][j], padded: conflict-free j-reads
    __shared__ float sB[ES];
    bool f32 = detect_f32(W1);
    int tt = threadIdx.x;
    for (int i = tt; i < ES * ES; i += BLK) sW2[(i >> 5) * 33 + (i & 31)] = ldv(W2, i, f32);
    if (tt < ES) sB[tt] = ldv(b2, tt, f32);
    __syncthreads();
    unsigned t = blockIdx.x * BLK + tt;
    if (t >= (unsigned)NPC * ES) return;
    int e = t >> 5, j = t & 31;
    int c = e + 1;
    int r = edges[2 * (NN + e)];
    float rc = rsqrtf((float)deg[c] + 1.f);
    float h = fmaxf(acc1[c * ES + j] + (rc * rc) * X[c * ES + j], 0.f);
    float x2 = sB[j];
    #pragma unroll
    for (int k = 0; k < ES; ++k)
        x2 += __shfl(h, k, ES) * sW2[k * 33 + j];
    float w = rsqrtf((float)deg[r] + 1.f) * rc;
    atomicAdd(&acc2[r * ES + j], w * x2);
}

// ---- k4: out[n] = relu(acc2[n] + (1/deg_n) * X2[n]); X2[n] recomputed.
// Output dtype follows input dtype (f32 path passed rounds 0-2,5-9).
__global__ __launch_bounds__(BLK)
void k4(const void* __restrict__ W1, const void* __restrict__ W2,
        const void* __restrict__ b2, const unsigned* __restrict__ deg,
        const float* __restrict__ acc1, const float* __restrict__ X,
        const float* __restrict__ acc2, void* __restrict__ out) {
    __shared__ float sW2[ES * 33];
    __shared__ float sB[ES];
    bool f32 = detect_f32(W1);
    int tt = threadIdx.x;
    for (int i = tt; i < ES * ES; i += BLK) sW2[(i >> 5) * 33 + (i & 31)] = ldv(W2, i, f32);
    if (tt < ES) sB[tt] = ldv(b2, tt, f32);
    __syncthreads();
    unsigned t = blockIdx.x * BLK + tt;               // exact grid: NN*ES threads
    int n = t >> 5, j = t & 31;
    float rn = rsqrtf((float)deg[n] + 1.f);
    float sw = rn * rn;
    float h = fmaxf(acc1[n * ES + j] + sw * X[n * ES + j], 0.f);
    float x2 = sB[j];
    #pragma unroll
    for (int k = 0; k < ES; ++k)
        x2 += __shfl(h, k, ES) * sW2[k * 33 + j];
    float v = fmaxf(acc2[n * ES + j] + sw * x2, 0.f);
    if (f32) ((float*)out)[t] = v;
    else     ((bf16*)out)[t]  = __float2bfloat16(v);
}

extern "C" void kernel_launch(void* const* d_in, const int* in_sizes, int n_in,
                              void* d_out, int out_size, void* d_ws, size_t ws_size,
                              hipStream_t stream) {
    const int* node_ids = (const int*)d_in[0];
    const int* edges    = (const int*)d_in[1];
    const void* table   = d_in[2];
    const void* W1      = d_in[3];
    const void* b1      = d_in[4];
    const void* W2      = d_in[5];
    const void* b2      = d_in[6];

    // ws layout: [deg u32 NN][acc1 f32 NN*ES][acc2 f32 NN*ES][X f32 NN*ES]
    char* ws = (char*)d_ws;
    unsigned* deg = (unsigned*)ws;
    float* acc1   = (float*)(ws + (size_t)NN * 4);
    float* acc2   = acc1 + (size_t)NN * ES;
    float* X      = acc2 + (size_t)NN * ES;

    const int g_mfma = NN / 64;                       // 192 blocks, 64 nodes each
    const int g_node = NN * ES / BLK;                 // 1536, exact
    const int g_edge = (NPC * ES + BLK - 1) / BLK;    // 1536, last block partial

    k1<<<g_mfma, BLK, 0, stream>>>(node_ids, edges, table, W1, b1, deg, X, (float4*)acc1);
    k2<<<g_edge, BLK, 0, stream>>>(edges, deg, X, acc1);
    k3<<<g_edge, BLK, 0, stream>>>(edges, W1, W2, b2, deg, acc1, X, acc2);
    k4<<<g_node, BLK, 0, stream>>>(W1, W2, b2, deg, acc1, X, acc2, d_out);
}